// Round 3
// baseline (17626.064 us; speedup 1.0000x reference)
//
#include <hip/hip_runtime.h>

#define D 512
#define H 16
#define HD 32
#define LAYERS 24
#define FF 2048
#define MAX_DECODE 1500
#define TOTAL 1024
#define CACHE_ROWS (TOTAL + MAX_DECODE)   // 2524
#define VOCAB_AUD 1025

typedef unsigned short u16;
typedef __attribute__((ext_vector_type(8))) __bf16 bf16x8;
typedef __attribute__((ext_vector_type(4))) float f32x4;
typedef __attribute__((ext_vector_type(8))) u16 u16x8;
typedef __attribute__((ext_vector_type(4))) u16 u16x4;

__device__ __forceinline__ u16 f2bf(float f) {
    unsigned u = __builtin_bit_cast(unsigned, f);
    u += 0x7fff + ((u >> 16) & 1);   // RNE
    return (u16)(u >> 16);
}

// ---------------------------------------------------------------------------
// Sinusoidal PE
// ---------------------------------------------------------------------------
__device__ __forceinline__ float pe_val(int pos, int c) {
    int j = c & ~1;
    float div = __expf((float)j * -0.017988946039015984f);  // -log(10000)/512
    float ang = (float)pos * div;
    return (c & 1) ? __cosf(ang) : __sinf(ang);
}

// ---------------------------------------------------------------------------
// Transpose + fp32->bf16 convert:  W[K][N] (layer z) -> WT[N][K] bf16
// ---------------------------------------------------------------------------
__global__ __launch_bounds__(256) void transpose_cvt(const float* __restrict__ W,
                                                     u16* __restrict__ WT,
                                                     int K, int N) {
    const size_t lsz = (size_t)K * N;
    const float* Wl = W + blockIdx.z * lsz;
    u16* WTl = WT + blockIdx.z * lsz;
    __shared__ float T[32][33];
    const int t = threadIdx.x;
    const int k0 = blockIdx.y * 32, n0 = blockIdx.x * 32;
    {
        int r = t >> 5, c = t & 31;
#pragma unroll
        for (int i = 0; i < 4; ++i)
            T[r + 8 * i][c] = Wl[(size_t)(k0 + r + 8 * i) * N + n0 + c];
    }
    __syncthreads();
    {
        int n = t >> 3, cg = t & 7;
        u16x4 o;
#pragma unroll
        for (int j = 0; j < 4; ++j) o[j] = f2bf(T[cg * 4 + j][n]);
        *(u16x4*)&WTl[(size_t)(n0 + n) * K + k0 + cg * 4] = o;
    }
}

// ---------------------------------------------------------------------------
// bf16 MFMA GEMM: C[M,N] = A[M,K] @ BT[N,K]^T + bias.
// 128x128 tile, BK=32, 256 thr (4 waves 2x2, each 64x64 = 16 MFMA frags).
// ---------------------------------------------------------------------------
#define AP 40  // LDS pitch (u16)

template <bool RELU, bool WF32, bool WBF16>
__global__ __launch_bounds__(256) void gemm_mfma(const u16* __restrict__ A,
                                                 const u16* __restrict__ BT,
                                                 const float* __restrict__ bias,
                                                 float* __restrict__ C,
                                                 u16* __restrict__ Cb,
                                                 int M, int K, int N) {
    __shared__ u16 As[128 * AP];
    __shared__ u16 Bs[128 * AP];
    const int tid = threadIdx.x;
    const int lane = tid & 63;
    const int wave = tid >> 6;
    const int wm = wave & 1, wn = wave >> 1;
    const int m0 = blockIdx.y * 128, n0 = blockIdx.x * 128;
    const int cr = lane & 15, qd = lane >> 4;
    f32x4 acc[4][4];
#pragma unroll
    for (int i = 0; i < 4; ++i)
#pragma unroll
        for (int j = 0; j < 4; ++j) acc[i][j] = (f32x4){0.f, 0.f, 0.f, 0.f};
    for (int k0 = 0; k0 < K; k0 += 32) {
#pragma unroll
        for (int i = 0; i < 2; ++i) {
            int slot = tid + i * 256;
            int r = slot >> 2, c = slot & 3;
            *(u16x8*)&As[r * AP + c * 8] =
                *(const u16x8*)&A[(size_t)(m0 + r) * K + k0 + c * 8];
            *(u16x8*)&Bs[r * AP + c * 8] =
                *(const u16x8*)&BT[(size_t)(n0 + r) * K + k0 + c * 8];
        }
        __syncthreads();
        bf16x8 af[4], bfr[4];
#pragma unroll
        for (int mi = 0; mi < 4; ++mi)
            af[mi] = *(const bf16x8*)&As[(wm * 64 + mi * 16 + cr) * AP + qd * 8];
#pragma unroll
        for (int ni = 0; ni < 4; ++ni)
            bfr[ni] = *(const bf16x8*)&Bs[(wn * 64 + ni * 16 + cr) * AP + qd * 8];
#pragma unroll
        for (int mi = 0; mi < 4; ++mi)
#pragma unroll
            for (int ni = 0; ni < 4; ++ni)
                acc[mi][ni] = __builtin_amdgcn_mfma_f32_16x16x32_bf16(
                    af[mi], bfr[ni], acc[mi][ni], 0, 0, 0);
        __syncthreads();
    }
#pragma unroll
    for (int mi = 0; mi < 4; ++mi)
#pragma unroll
        for (int ni = 0; ni < 4; ++ni) {
            int n = n0 + wn * 64 + ni * 16 + cr;
            float bn = bias[n];
#pragma unroll
            for (int r = 0; r < 4; ++r) {
                int mm = m0 + wm * 64 + mi * 16 + qd * 4 + r;
                float v = acc[mi][ni][r] + bn;
                if (RELU) v = fmaxf(v, 0.f);
                if (WF32) C[(size_t)mm * N + n] = v;
                if (WBF16) Cb[(size_t)mm * N + n] = f2bf(v);
            }
        }
}

// ---------------------------------------------------------------------------
// Build packed input h (fp32 + bf16)
// ---------------------------------------------------------------------------
__global__ void build_h(const int* __restrict__ prompts, const int* __restrict__ pl,
                        const int* __restrict__ ref_seq, const int* __restrict__ rl,
                        const int* __restrict__ text_seq, const int* __restrict__ tl,
                        const float* __restrict__ text_emb, const float* __restrict__ audio_emb,
                        const float* __restrict__ refproj, const float* __restrict__ textproj,
                        const float* __restrict__ alpha_text, const float* __restrict__ alpha_audio,
                        float* __restrict__ h, u16* __restrict__ hb) {
    const int t = blockIdx.x;
    const int ref_len = rl[0], text_len = tl[0], p_len = pl[0];
    const int x_len = ref_len + text_len;
    const int tot = x_len + p_len;
    const float at = alpha_text[0], aa = alpha_audio[0];
    for (int c = threadIdx.x; c < D; c += 256) {
        float val = 0.f;
        if (t < x_len) {
            float pe = at * pe_val(t, c);
            if (t < ref_len)
                val = text_emb[ref_seq[t] * D + c] + refproj[t * D + c] + pe;
            else
                val = text_emb[text_seq[t - ref_len] * D + c] + textproj[(t - ref_len) * D + c] + pe;
        } else if (t < tot) {
            int i = t - x_len;
            float pe = aa * pe_val(i, c);
            float a = (i < p_len) ? audio_emb[prompts[i] * D + c] : 0.f;
            val = a + pe;
        }
        h[t * D + c] = val;
        hb[t * D + c] = f2bf(val);
    }
}

// ---------------------------------------------------------------------------
// Copy k,v slices of qkv buffer into the layer's cache rows.
// ---------------------------------------------------------------------------
__global__ void copy_kv(const float* __restrict__ qkv, float* __restrict__ kc,
                        float* __restrict__ vc) {
    int idx = blockIdx.x * 256 + threadIdx.x;
    int row = idx >> 7, c4 = idx & 127;
    const float4* kp = (const float4*)(qkv + row * (3 * D) + D);
    const float4* vp = (const float4*)(qkv + row * (3 * D) + 2 * D);
    ((float4*)(kc + row * D))[c4] = kp[c4];
    ((float4*)(vc + row * D))[c4] = vp[c4];
}

__global__ void zero_pads(float* __restrict__ kc, float* __restrict__ vc) {
    const int per_layer = MAX_DECODE * D / 4;
    int idx = blockIdx.x * 256 + threadIdx.x;
    int l = idx / per_layer, r = idx % per_layer;
    if (l >= LAYERS) return;
    float4 z = {0.f, 0.f, 0.f, 0.f};
    float* kbase = kc + (size_t)l * CACHE_ROWS * D + (size_t)TOTAL * D;
    float* vbase = vc + (size_t)l * CACHE_ROWS * D + (size_t)TOTAL * D;
    ((float4*)kbase)[r] = z;
    ((float4*)vbase)[r] = z;
}

// ---------------------------------------------------------------------------
// Attention v3: block = (head, 32-q tile), 256 thr. K/V in LDS (128-key
// chunks), online softmax in groups of 8 scores (register-lean, no spills),
// 8-way key-partition combine in LDS. Output bf16.
// ---------------------------------------------------------------------------
__global__ __launch_bounds__(256) void attn3(const float* __restrict__ qkv,
                                             const int* __restrict__ rl,
                                             const int* __restrict__ tl,
                                             const int* __restrict__ pl,
                                             u16* __restrict__ outb) {
    __shared__ float smem[9216];  // K[128][36] | V[128][36]; aliased combine[8][32][36]
    const int head = blockIdx.x;
    const int q0 = blockIdx.y * 32;
    const int t = threadIdx.x;
    const int qq = t & 31, p = t >> 5;  // p in 0..7
    const int qi = q0 + qq;
    const int xl = rl[0] + tl[0];
    const int tot = xl + pl[0];
    const bool vq = qi < tot;
    const float scale = 0.17677669529663687f;  // 1/sqrt(32)
    const float* qp = qkv + (size_t)qi * 1536 + head * HD;
    f32x4 qv[8];
#pragma unroll
    for (int c = 0; c < 8; ++c) qv[c] = *(const f32x4*)(qp + c * 4);
    f32x4 o[8];
#pragma unroll
    for (int c = 0; c < 8; ++c) o[c] = (f32x4){0.f, 0.f, 0.f, 0.f};
    float m = -3.0e38f, l = 0.f;
    for (int kt = 0; kt < 8; ++kt) {
        {   // stage 128 keys of K and V
            int row = t >> 1, half = t & 1;
            const float* kp = qkv + (size_t)(kt * 128 + row) * 1536 + 512 + head * HD + half * 16;
            const float* vp = kp + 512;
#pragma unroll
            for (int i = 0; i < 4; ++i) {
                *(f32x4*)&smem[row * 36 + half * 16 + i * 4] = *(const f32x4*)(kp + i * 4);
                *(f32x4*)&smem[4608 + row * 36 + half * 16 + i * 4] = *(const f32x4*)(vp + i * 4);
            }
        }
        __syncthreads();
#pragma unroll
        for (int g = 0; g < 2; ++g) {   // 2 groups of 8 keys per partition
            float sc[8];
            float tmax = -3.0e38f;
#pragma unroll
            for (int j = 0; j < 8; ++j) {
                int kk = p * 16 + g * 8 + j;
                const float* kr = &smem[kk * 36];
                f32x4 a0 = (f32x4){0.f, 0.f, 0.f, 0.f};
                f32x4 a1 = (f32x4){0.f, 0.f, 0.f, 0.f};
#pragma unroll
                for (int c = 0; c < 4; ++c) {
                    a0 += qv[2 * c] * *(const f32x4*)(kr + 8 * c);
                    a1 += qv[2 * c + 1] * *(const f32x4*)(kr + 8 * c + 4);
                }
                f32x4 a = a0 + a1;
                float s = (a.x + a.y + a.z + a.w) * scale;
                int kg = kt * 128 + kk;
                bool vk = kg < tot;
                bool inv = (!vq) || (!vk) ||
                           ((qi < xl) ? (kg >= xl) : ((kg >= xl) && (kg > qi)));
                s = inv ? -1.0e9f : s;
                sc[j] = s;
                tmax = fmaxf(tmax, s);
            }
            float mn = fmaxf(m, tmax);
            float f = __expf(m - mn);
            l *= f;
#pragma unroll
            for (int c = 0; c < 8; ++c) o[c] *= f;
#pragma unroll
            for (int j = 0; j < 8; ++j) {
                float pw = __expf(sc[j] - mn);
                l += pw;
                const float* vr = &smem[4608 + (p * 16 + g * 8 + j) * 36];
#pragma unroll
                for (int c = 0; c < 8; ++c) o[c] += pw * *(const f32x4*)(vr + c * 4);
            }
            m = mn;
        }
        __syncthreads();
    }
    {   // write partials: [p][qq]: m, l, _, _, o0..o31  (stride 36)
        int base = (p * 32 + qq) * 36;
        smem[base] = m;
        smem[base + 1] = l;
#pragma unroll
        for (int c = 0; c < 8; ++c) *(f32x4*)&smem[base + 4 + c * 4] = o[c];
    }
    __syncthreads();
    {   // combine: 8 threads per q row, 4 dims each
        int dc = t >> 5;   // 0..7
        int q2 = t & 31;
        float mp[8];
        float M2 = -3.0e38f;
#pragma unroll
        for (int pp = 0; pp < 8; ++pp) {
            mp[pp] = smem[(pp * 32 + q2) * 36];
            M2 = fmaxf(M2, mp[pp]);
        }
        float L = 0.f, w[8];
#pragma unroll
        for (int pp = 0; pp < 8; ++pp) {
            w[pp] = __expf(mp[pp] - M2);
            L += smem[(pp * 32 + q2) * 36 + 1] * w[pp];
        }
        float invL = 1.f / L;
        u16x4 ov;
#pragma unroll
        for (int j = 0; j < 4; ++j) {
            int d = dc * 4 + j;
            float val = 0.f;
#pragma unroll
            for (int pp = 0; pp < 8; ++pp)
                val += smem[(pp * 32 + q2) * 36 + 4 + d] * w[pp];
            ov[j] = f2bf(val * invL);
        }
        *(u16x4*)&outb[(size_t)(q0 + q2) * D + head * HD + dc * 4] = ov;
    }
}

// ---------------------------------------------------------------------------
// h = LayerNorm(res + proj) * w + b  -> fp32 h AND bf16 hb
// ---------------------------------------------------------------------------
__global__ __launch_bounds__(256) void add_ln(const float* __restrict__ res,
                                              const float* __restrict__ proj,
                                              const float* __restrict__ lw,
                                              const float* __restrict__ lb,
                                              float* __restrict__ hout,
                                              u16* __restrict__ hbout) {
    const int row = blockIdx.x, tid = threadIdx.x;
    __shared__ float red[8];
    const float x0 = res[row * D + tid] + proj[row * D + tid];
    const float x1 = res[row * D + tid + 256] + proj[row * D + tid + 256];
    float s = x0 + x1, s2 = x0 * x0 + x1 * x1;
    for (int o = 32; o > 0; o >>= 1) {
        s += __shfl_down(s, o);
        s2 += __shfl_down(s2, o);
    }
    if ((tid & 63) == 0) {
        red[tid >> 6] = s;
        red[4 + (tid >> 6)] = s2;
    }
    __syncthreads();
    const float mean = (red[0] + red[1] + red[2] + red[3]) * (1.f / 512.f);
    const float var = (red[4] + red[5] + red[6] + red[7]) * (1.f / 512.f) - mean * mean;
    const float r = rsqrtf(var + 1e-5f);
    float y0 = (x0 - mean) * r * lw[tid] + lb[tid];
    float y1 = (x1 - mean) * r * lw[tid + 256] + lb[tid + 256];
    hout[row * D + tid] = y0;
    hout[row * D + tid + 256] = y1;
    hbout[row * D + tid] = f2bf(y0);
    hbout[row * D + tid + 256] = f2bf(y1);
}

// ---------------------------------------------------------------------------
__global__ void logits_kernel(const float* __restrict__ h, const float* __restrict__ pw,
                              const float* __restrict__ pb, const int* __restrict__ rl,
                              const int* __restrict__ tl, const int* __restrict__ pl,
                              float* __restrict__ out) {
    const int n = blockIdx.x * 256 + threadIdx.x;
    if (n >= VOCAB_AUD) return;
    int tot = rl[0] + tl[0] + pl[0];
    int last = tot - 1;
    if (last < 0) last = 0;
    const float* hr = h + last * D;
    float acc = 0.f;
    for (int d = 0; d < D; ++d) acc += hr[d] * pw[d * VOCAB_AUD + n];
    out[n] = acc + pb[n];
}

__global__ void finalize_kernel(const float* __restrict__ logits, const int* __restrict__ rl,
                                const int* __restrict__ tl, const int* __restrict__ pl,
                                float* __restrict__ out) {
    __shared__ float vals[1024];
    __shared__ int idxs[1024];
    const int tid = threadIdx.x;
    float v = logits[tid];
    int bi = tid;
    if (tid == 0 && logits[1024] > v) { v = logits[1024]; bi = 1024; }
    vals[tid] = v;
    idxs[tid] = bi;
    __syncthreads();
    for (int s2 = 512; s2 > 0; s2 >>= 1) {
        if (tid < s2) {
            float ov = vals[tid + s2];
            int oi = idxs[tid + s2];
            if (ov > vals[tid] || (ov == vals[tid] && oi < idxs[tid])) {
                vals[tid] = ov;
                idxs[tid] = oi;
            }
        }
        __syncthreads();
    }
    if (tid == 0) {
        out[1025] = (float)idxs[0];
        out[1026] = (idxs[0] == 1024) ? 1.f : 0.f;
        out[1027] = (float)(rl[0] + tl[0] + pl[0]);
        out[1028] = (float)pl[0];
    }
}

// ---------------------------------------------------------------------------
extern "C" void kernel_launch(void* const* d_in, const int* in_sizes, int n_in,
                              void* d_out, int out_size, void* d_ws, size_t ws_size,
                              hipStream_t stream) {
    const int* prompts = (const int*)d_in[0];
    const int* p_len = (const int*)d_in[1];
    const int* ref_seq = (const int*)d_in[2];
    const int* r_len = (const int*)d_in[3];
    const int* text_seq = (const int*)d_in[4];
    const int* t_len = (const int*)d_in[5];
    const float* ref_bert = (const float*)d_in[6];
    const float* text_bert = (const float*)d_in[7];
    const float* text_emb = (const float*)d_in[8];
    const float* audio_emb = (const float*)d_in[9];
    const float* bert_w = (const float*)d_in[10];
    const float* bert_b = (const float*)d_in[11];
    const float* alpha_text = (const float*)d_in[12];
    const float* alpha_audio = (const float*)d_in[13];
    const float* qkv_w = (const float*)d_in[14];
    const float* qkv_b = (const float*)d_in[15];
    const float* out_w = (const float*)d_in[16];
    const float* out_b = (const float*)d_in[17];
    const float* ln1_w = (const float*)d_in[18];
    const float* ln1_b = (const float*)d_in[19];
    const float* ff1_w = (const float*)d_in[20];
    const float* ff1_b = (const float*)d_in[21];
    const float* ff2_w = (const float*)d_in[22];
    const float* ff2_b = (const float*)d_in[23];
    const float* ln2_w = (const float*)d_in[24];
    const float* ln2_b = (const float*)d_in[25];
    const float* pred_w = (const float*)d_in[26];
    const float* pred_b = (const float*)d_in[27];

    // ---- workspace carve-up ----
    float* ws = (float*)d_ws;
    float* h = ws;                       // 524288 f
    float* proj = h + 524288;            // 524288 f
    float* qkvb = proj + 524288;         // 1572864 f
    float* refp = qkvb + 1572864;        // 131072 f
    float* textp = refp + 131072;        // 131072 f
    u16* hb = (u16*)(textp + 131072);    // 524288 u
    u16* attn_ob = hb + 524288;          // 524288 u
    u16* ffb = attn_ob + 524288;         // 2097152 u
    u16* refT = ffb + 2097152;           // 262144 u
    u16* textT = refT + 262144;          // 262144 u
    u16* bertwT = textT + 262144;        // 524288 u
    u16* wbase = bertwT + 524288;

    const size_t W_QKV = (size_t)D * 3 * D;
    const size_t W_OUT = (size_t)D * D;
    const size_t W_FF1 = (size_t)D * FF;
    const size_t W_FF2 = (size_t)FF * D;
    const size_t W_ALL = W_QKV + W_OUT + W_FF1 + W_FF2;

    const size_t need_full = ((char*)(wbase + LAYERS * W_ALL) - (char*)ws);
    const bool full = ws_size >= need_full;

    u16* qkvT = wbase;
    u16* outT = qkvT + (full ? LAYERS * W_QKV : 0);
    u16* ff1T = outT + (full ? LAYERS * W_OUT : 0);
    u16* ff2T = ff1T + (full ? LAYERS * W_FF1 : 0);
    if (!full) {
        qkvT = wbase;
        outT = qkvT + W_QKV;
        ff1T = outT + W_OUT;
        ff2T = ff1T + W_FF1;
    }

    float* out = (float*)d_out;
    float* kc = out + 1029;
    float* vc = out + 1029 + (size_t)LAYERS * CACHE_ROWS * D;

    {
        int total4 = LAYERS * (MAX_DECODE * D / 4);
        zero_pads<<<(total4 + 255) / 256, 256, 0, stream>>>(kc, vc);
    }

    transpose_cvt<<<dim3(256 / 32, 1024 / 32, 1), 256, 0, stream>>>(ref_bert, refT, 1024, 256);
    transpose_cvt<<<dim3(256 / 32, 1024 / 32, 1), 256, 0, stream>>>(text_bert, textT, 1024, 256);
    transpose_cvt<<<dim3(D / 32, 1024 / 32, 1), 256, 0, stream>>>(bert_w, bertwT, 1024, D);
    if (full) {
        transpose_cvt<<<dim3(3 * D / 32, D / 32, LAYERS), 256, 0, stream>>>(qkv_w, qkvT, D, 3 * D);
        transpose_cvt<<<dim3(D / 32, D / 32, LAYERS), 256, 0, stream>>>(out_w, outT, D, D);
        transpose_cvt<<<dim3(FF / 32, D / 32, LAYERS), 256, 0, stream>>>(ff1_w, ff1T, D, FF);
        transpose_cvt<<<dim3(D / 32, FF / 32, LAYERS), 256, 0, stream>>>(ff2_w, ff2T, FF, D);
    }

    gemm_mfma<false, true, false><<<dim3(D / 128, 256 / 128), 256, 0, stream>>>(
        refT, bertwT, bert_b, refp, nullptr, 256, 1024, D);
    gemm_mfma<false, true, false><<<dim3(D / 128, 256 / 128), 256, 0, stream>>>(
        textT, bertwT, bert_b, textp, nullptr, 256, 1024, D);

    build_h<<<TOTAL, 256, 0, stream>>>(prompts, p_len, ref_seq, r_len, text_seq, t_len,
                                       text_emb, audio_emb, refp, textp,
                                       alpha_text, alpha_audio, h, hb);

    for (int l = 0; l < LAYERS; ++l) {
        u16 *wQ, *wO, *wF1, *wF2;
        if (full) {
            wQ = qkvT + l * W_QKV;
            wO = outT + l * W_OUT;
            wF1 = ff1T + l * W_FF1;
            wF2 = ff2T + l * W_FF2;
        } else {
            transpose_cvt<<<dim3(3 * D / 32, D / 32, 1), 256, 0, stream>>>(
                qkv_w + l * W_QKV, qkvT, D, 3 * D);
            transpose_cvt<<<dim3(D / 32, D / 32, 1), 256, 0, stream>>>(
                out_w + l * W_OUT, outT, D, D);
            transpose_cvt<<<dim3(FF / 32, D / 32, 1), 256, 0, stream>>>(
                ff1_w + l * W_FF1, ff1T, D, FF);
            transpose_cvt<<<dim3(D / 32, FF / 32, 1), 256, 0, stream>>>(
                ff2_w + l * W_FF2, ff2T, FF, D);
            wQ = qkvT; wO = outT; wF1 = ff1T; wF2 = ff2T;
        }
        gemm_mfma<false, true, false><<<dim3(3 * D / 128, TOTAL / 128), 256, 0, stream>>>(
            hb, wQ, qkv_b + (size_t)l * 3 * D, qkvb, nullptr, TOTAL, D, 3 * D);
        copy_kv<<<TOTAL * (D / 4) / 256, 256, 0, stream>>>(
            qkvb, kc + (size_t)l * CACHE_ROWS * D, vc + (size_t)l * CACHE_ROWS * D);
        attn3<<<dim3(H, TOTAL / 32), 256, 0, stream>>>(qkvb, r_len, t_len, p_len, attn_ob);
        gemm_mfma<false, true, false><<<dim3(D / 128, TOTAL / 128), 256, 0, stream>>>(
            attn_ob, wO, out_b + (size_t)l * D, proj, TOTAL ? nullptr : nullptr, TOTAL, D, D);
        add_ln<<<TOTAL, 256, 0, stream>>>(h, proj, ln1_w + l * D, ln1_b + l * D, h, hb);
        gemm_mfma<true, false, true><<<dim3(FF / 128, TOTAL / 128), 256, 0, stream>>>(
            hb, wF1, ff1_b + (size_t)l * FF, nullptr, ffb, TOTAL, D, FF);
        gemm_mfma<false, true, false><<<dim3(D / 128, TOTAL / 128), 256, 0, stream>>>(
            ffb, wF2, ff2_b + (size_t)l * D, proj, nullptr, TOTAL, FF, D);
        add_ln<<<TOTAL, 256, 0, stream>>>(h, proj, ln2_w + l * D, ln2_b + l * D, h, hb);
    }

    logits_kernel<<<(VOCAB_AUD + 255) / 256, 256, 0, stream>>>(
        h, pred_w, pred_b, r_len, t_len, p_len, out);
    finalize_kernel<<<1, 1024, 0, stream>>>(out, r_len, t_len, p_len, out);
}